// Round 12
// baseline (740.976 us; speedup 1.0000x reference)
//
#include <hip/hip_runtime.h>

#define HDIM 192
#define EPS 1e-5f

typedef __attribute__((ext_vector_type(8))) _Float16 half8;
typedef __attribute__((ext_vector_type(4))) float floatx4;

__device__ __forceinline__ float h2f(ushort u) {
    union { ushort u; _Float16 h; } c; c.u = u; return (float)c.h;
}
__device__ __forceinline__ ushort f2h(float x) {
    _Float16 h = (_Float16)x;           // RTN
    union { _Float16 h; ushort u; } c; c.h = h; return c.u;
}
__device__ __forceinline__ uint4 pack8(const ushort* h) {
    uint4 p;
    p.x = h[0] | ((uint)h[1] << 16); p.y = h[2] | ((uint)h[3] << 16);
    p.z = h[4] | ((uint)h[5] << 16); p.w = h[6] | ((uint)h[7] << 16);
    return p;
}

// Activation planes are CHUNK-PLANAR: element (row, c) lives at
// ((c/32)*Nrow + row)*32 + c%32.  GEMM A-frag loads read a contiguous 1KB
// block per wave; GEMM C-writes, bn/gather all use the same layout.

// ---------------------------------------------------------------------------
// Weight prep: W[K,192] fp32 (nmat stacked) -> frag-ordered SINGLE fp16 plane.
// Per k-chunk (32 k): [ct(12)][lane(64)][j(8)] = 6144 ushorts.
// ---------------------------------------------------------------------------
__global__ __launch_bounds__(256) void prep_w_k(
    const float* __restrict__ W, ushort* __restrict__ Wf, int K, int nmat)
{
    int perMat = (K >> 5) * 12 * 64;
    int idx = blockIdx.x * 256 + threadIdx.x;
    if (idx >= perMat * nmat) return;
    int mat = idx / perMat;
    int r = idx - mat * perMat;
    int lane = r & 63;
    int ct = (r >> 6) % 12;
    int kc = r / (12 * 64);
    int col = ct * 16 + (lane & 15);
    int kb  = kc * 32 + (lane >> 4) * 8;
    const float* Wm = W + (size_t)mat * K * HDIM;
    ushort* base = Wf + (size_t)mat * K * HDIM;
    size_t o = (size_t)kc * 6144 + (size_t)(ct * 64 + lane) * 8;
    #pragma unroll
    for (int j = 0; j < 8; ++j)
        base[o + j] = f2h(Wm[(size_t)(kb + j) * HDIM + col]);
}

// ---------------------------------------------------------------------------
// fp32 row-major [R, C] -> fp16 chunk-planar. One thread per 8 channels.
// ---------------------------------------------------------------------------
__global__ __launch_bounds__(256) void conv_planar_k(
    const float* __restrict__ src, ushort* __restrict__ dst, int R, int C)
{
    int OC = C >> 3;
    int idx = blockIdx.x * 256 + threadIdx.x;
    if (idx >= R * OC) return;
    int r = idx / OC;
    int o = idx - r * OC;
    float4 v0 = ((const float4*)(src + (size_t)r * C + o * 8))[0];
    float4 v1 = ((const float4*)(src + (size_t)r * C + o * 8))[1];
    float v[8] = {v0.x, v0.y, v0.z, v0.w, v1.x, v1.y, v1.z, v1.w};
    ushort h[8];
    #pragma unroll
    for (int t = 0; t < 8; ++t) h[t] = f2h(v[t]);
    *(uint4*)(dst + ((size_t)(o >> 2) * R + r) * 32 + (o & 3) * 8) = pack8(h);
}

// ---------------------------------------------------------------------------
// MFMA GEMM: C[N,192] = A1@W1 (+ A2@W2) + bias-term, optional fused BN stats.
// Block: 256 thr / 4 waves, tile 128 rows x 192 cols; wave tile 64x96
// (r2=wave&1 row half, c2=wave>>1 col half).  acc=96, ~151 unified regs.
// Per wave-chunk: 4 A + 6 B b128 loads, 24 MFMA (0.42 loads/MFMA).
// A chunk-planar fp16; W single fp16 plane frag-major; straight from global,
// no LDS staging, no K-loop barriers, no prefetch (register headroom).
// C written fp16 CHUNK-PLANAR (BN stats taken from fp32 accumulators).
// ---------------------------------------------------------------------------
template<bool DUAL, bool RELU, bool DEG, bool STATS>
__global__ __launch_bounds__(256, 3) void gemm_mfma_k(
    const ushort* __restrict__ A1h, const ushort* __restrict__ W1f,
    const ushort* __restrict__ A2h, const ushort* __restrict__ W2f,
    const float* __restrict__ degf, const float* __restrict__ bias,
    ushort* __restrict__ C, float* __restrict__ stats, int N, int K)
{
    __shared__ float sstat[2][HDIM];
    const int tid  = threadIdx.x;
    const int wave = tid >> 6;
    const int lane = tid & 63;
    const int r2 = wave & 1;
    const int c2 = wave >> 1;
    const int row0 = blockIdx.x * 128 + r2 * 64;
    const int m16 = lane & 15;
    const int g4  = lane >> 4;

    if (STATS && tid < HDIM) { sstat[0][tid] = 0.f; sstat[1][tid] = 0.f; }

    int rowid[4];
    #pragma unroll
    for (int s = 0; s < 4; ++s) {
        int rr = row0 + s * 16 + m16; if (rr >= N) rr = N - 1;
        rowid[s] = rr;
    }

    floatx4 acc[4][6];
    #pragma unroll
    for (int s = 0; s < 4; ++s)
        #pragma unroll
        for (int ct = 0; ct < 6; ++ct) acc[s][ct] = (floatx4){0.f, 0.f, 0.f, 0.f};

    const int nkc = K >> 5;
    const int nphase = DUAL ? 2 : 1;
    for (int phase = 0; phase < nphase; ++phase) {
        const ushort* Ah = phase ? A2h : A1h;
        const ushort* Wf = phase ? W2f : W1f;
        for (int kc = 0; kc < nkc; ++kc) {
            const ushort* Bp = Wf + (size_t)kc * 6144
                             + (size_t)(c2 * 6 * 64 + lane) * 8;
            half8 b[6];
            #pragma unroll
            for (int ct = 0; ct < 6; ++ct)
                b[ct] = *(const half8*)(Bp + ct * 512);
            const ushort* Ap = Ah + (size_t)kc * N * 32 + g4 * 8;
            half8 a[4];
            #pragma unroll
            for (int s = 0; s < 4; ++s)
                a[s] = *(const half8*)(Ap + (size_t)rowid[s] * 32);
            #pragma unroll
            for (int ct = 0; ct < 6; ++ct)
                #pragma unroll
                for (int s = 0; s < 4; ++s)
                    acc[s][ct] = __builtin_amdgcn_mfma_f32_16x16x32_f16(a[s], b[ct], acc[s][ct], 0, 0, 0);
        }
    }

    if (STATS) __syncthreads();   // sstat zero-init visible

    // epilogue: C/D layout col=lane&15, row=(lane>>4)*4+reg  [m89]
    // C written fp16 chunk-planar: ((col/32)*N + rr)*32 + col%32
    #pragma unroll
    for (int ct = 0; ct < 6; ++ct) {
        int col = c2 * 96 + ct * 16 + m16;
        float bv = bias ? bias[col] : 0.f;
        ushort* Cc = C + (size_t)(col >> 5) * N * 32 + (col & 31);
        float lsum = 0.f, lsq = 0.f;
        #pragma unroll
        for (int s = 0; s < 4; ++s) {
            #pragma unroll
            for (int reg = 0; reg < 4; ++reg) {
                int rr = row0 + s * 16 + g4 * 4 + reg;
                if (rr < N) {
                    float v = acc[s][ct][reg] + (DEG ? degf[rr] * bv : bv);
                    if (STATS) { lsum += v; lsq += v * v; }
                    if (RELU) v = fmaxf(v, 0.f);
                    Cc[(size_t)rr * 32] = f2h(v);
                }
            }
        }
        if (STATS) {
            lsum += __shfl_xor(lsum, 16); lsum += __shfl_xor(lsum, 32);
            lsq  += __shfl_xor(lsq, 16);  lsq  += __shfl_xor(lsq, 32);
            if (g4 == 0) {
                atomicAdd(&sstat[0][col], lsum);
                atomicAdd(&sstat[1][col], lsq);
            }
        }
    }
    if (STATS) {
        __syncthreads();
        if (tid < HDIM) {
            atomicAdd(&stats[tid], sstat[0][tid]);
            atomicAdd(&stats[HDIM + tid], sstat[1][tid]);
        }
    }
}

// ---------------------------------------------------------------------------
// CSR construction from edge_dst
// ---------------------------------------------------------------------------
__global__ __launch_bounds__(256) void hist_k(
    const int* __restrict__ dst, int* __restrict__ deg, int E)
{
    int e = blockIdx.x * 256 + threadIdx.x;
    if (e < E) atomicAdd(&deg[dst[e]], 1);
}

__global__ __launch_bounds__(256) void block_sum_k(
    const int* __restrict__ deg, int* __restrict__ bsum, int N)
{
    __shared__ int s[256];
    int t = threadIdx.x;
    int n = blockIdx.x * 256 + t;
    s[t] = (n < N) ? deg[n] : 0;
    __syncthreads();
    for (int off = 128; off > 0; off >>= 1) {
        if (t < off) s[t] += s[t + off];
        __syncthreads();
    }
    if (t == 0) bsum[blockIdx.x] = s[0];
}

__global__ __launch_bounds__(512) void scan_bsum_k(int* __restrict__ bsum, int nb)
{
    __shared__ int s[512];
    int t = threadIdx.x;
    int v = (t < nb) ? bsum[t] : 0;
    s[t] = v;
    __syncthreads();
    for (int off = 1; off < 512; off <<= 1) {
        int u = (t >= off) ? s[t - off] : 0;
        __syncthreads();
        s[t] += u;
        __syncthreads();
    }
    if (t < nb) bsum[t] = s[t] - v;   // exclusive
}

__global__ __launch_bounds__(256) void row_ptr_k(
    const int* __restrict__ deg, const int* __restrict__ bsum,
    int* __restrict__ row_ptr, int* __restrict__ cursor,
    float* __restrict__ degf, int N, int E)
{
    __shared__ int s[256];
    int t = threadIdx.x;
    int n = blockIdx.x * 256 + t;
    int v = (n < N) ? deg[n] : 0;
    s[t] = v;
    __syncthreads();
    for (int off = 1; off < 256; off <<= 1) {
        int u = (t >= off) ? s[t - off] : 0;
        __syncthreads();
        s[t] += u;
        __syncthreads();
    }
    int ex = s[t] - v + bsum[blockIdx.x];
    if (n < N) {
        row_ptr[n] = ex;
        cursor[n]  = ex;
        degf[n]    = (float)v;
    }
    if (blockIdx.x == 0 && t == 0) row_ptr[N] = E;
}

__global__ __launch_bounds__(256) void fill_k(
    const int* __restrict__ src, const int* __restrict__ dst,
    int* __restrict__ cursor, int* __restrict__ col, int E)
{
    int e = blockIdx.x * 256 + threadIdx.x;
    if (e < E) {
        int p = atomicAdd(&cursor[dst[e]], 1);
        col[p] = src[e];
    }
}

// ---------------------------------------------------------------------------
// plain gather (layer 0, no BN): g[n] = sum_j x[col[j]]; planar fp16.
// ---------------------------------------------------------------------------
__global__ __launch_bounds__(256) void gather_h_k(
    const ushort* __restrict__ xh, const int* __restrict__ row_ptr,
    const int* __restrict__ col, ushort* __restrict__ gh, int N, int K)
{
    int OC = K >> 3;
    int idx = blockIdx.x * 256 + threadIdx.x;
    if (idx >= N * OC) return;
    int n = idx / OC;
    int o = idx - n * OC;
    size_t plane = (size_t)(o >> 2) * N * 32 + (o & 3) * 8;
    int j0 = row_ptr[n], j1 = row_ptr[n + 1];
    float acc[8] = {0.f,0.f,0.f,0.f,0.f,0.f,0.f,0.f};
    for (int j = j0; j < j1; ++j) {
        int s = col[j];
        uint4 hv = *(const uint4*)(xh + plane + (size_t)s * 32);
        uint hu[4] = {hv.x, hv.y, hv.z, hv.w};
        #pragma unroll
        for (int t = 0; t < 4; ++t) {
            acc[2*t]   += h2f((ushort)(hu[t] & 0xffffu));
            acc[2*t+1] += h2f((ushort)(hu[t] >> 16));
        }
    }
    ushort oh[8];
    #pragma unroll
    for (int t = 0; t < 8; ++t) oh[t] = f2h(acc[t]);
    *(uint4*)(gh + plane + (size_t)n * 32) = pack8(oh);
}

// ---------------------------------------------------------------------------
// fused BN-apply + gather (layers 1..3, K=192): reads raw conv h (planar),
// computes per-thread BN coeffs from raw sums (kills bn_finalize), writes
// xh[n] = relu(bn(h[n])) and gh[n] = sum_j relu(bn(h[col j])).
// ---------------------------------------------------------------------------
__global__ __launch_bounds__(256) void gather_bn_k(
    const ushort* __restrict__ h, const float* __restrict__ stats,
    const float* __restrict__ gamma, const float* __restrict__ beta,
    float invN, const int* __restrict__ row_ptr, const int* __restrict__ col,
    ushort* __restrict__ xh, ushort* __restrict__ gh, int N)
{
    int idx = blockIdx.x * 256 + threadIdx.x;
    if (idx >= N * 24) return;
    int n = idx / 24;
    int o = idx - n * 24;
    int q = o * 8;
    float sc[8], sh[8];
    #pragma unroll
    for (int t = 0; t < 8; ++t) {
        float mu  = stats[q + t] * invN;
        float var = stats[HDIM + q + t] * invN - mu * mu;
        float s = gamma[q + t] * rsqrtf(var + EPS);
        sc[t] = s; sh[t] = beta[q + t] - mu * s;
    }
    size_t plane = (size_t)(o >> 2) * N * 32 + (o & 3) * 8;
    // own row -> xh
    {
        uint4 hv = *(const uint4*)(h + plane + (size_t)n * 32);
        uint hu[4] = {hv.x, hv.y, hv.z, hv.w};
        ushort oh[8];
        #pragma unroll
        for (int t = 0; t < 4; ++t) {
            float v0 = h2f((ushort)(hu[t] & 0xffffu));
            float v1 = h2f((ushort)(hu[t] >> 16));
            oh[2*t]   = f2h(fmaxf(v0 * sc[2*t]   + sh[2*t],   0.f));
            oh[2*t+1] = f2h(fmaxf(v1 * sc[2*t+1] + sh[2*t+1], 0.f));
        }
        *(uint4*)(xh + plane + (size_t)n * 32) = pack8(oh);
    }
    // neighbors -> gh
    int j0 = row_ptr[n], j1 = row_ptr[n + 1];
    float acc[8] = {0.f,0.f,0.f,0.f,0.f,0.f,0.f,0.f};
    for (int j = j0; j < j1; ++j) {
        int s = col[j];
        uint4 hv = *(const uint4*)(h + plane + (size_t)s * 32);
        uint hu[4] = {hv.x, hv.y, hv.z, hv.w};
        #pragma unroll
        for (int t = 0; t < 4; ++t) {
            float v0 = h2f((ushort)(hu[t] & 0xffffu));
            float v1 = h2f((ushort)(hu[t] >> 16));
            acc[2*t]   += fmaxf(v0 * sc[2*t]   + sh[2*t],   0.f);
            acc[2*t+1] += fmaxf(v1 * sc[2*t+1] + sh[2*t+1], 0.f);
        }
    }
    ushort oh[8];
    #pragma unroll
    for (int t = 0; t < 8; ++t) oh[t] = f2h(acc[t]);
    *(uint4*)(gh + plane + (size_t)n * 32) = pack8(oh);
}

// ---------------------------------------------------------------------------
// BN-apply only (after last layer): xh = relu(bn(h)), per-thread coeffs.
// ---------------------------------------------------------------------------
__global__ __launch_bounds__(256) void bn_apply_h_k(
    const ushort* __restrict__ h, const float* __restrict__ stats,
    const float* __restrict__ gamma, const float* __restrict__ beta,
    float invN, ushort* __restrict__ xh, int N)
{
    int idx = blockIdx.x * 256 + threadIdx.x;
    if (idx >= N * 24) return;
    int n = idx / 24;
    int o = idx - n * 24;
    int q = o * 8;
    float sc[8], sh[8];
    #pragma unroll
    for (int t = 0; t < 8; ++t) {
        float mu  = stats[q + t] * invN;
        float var = stats[HDIM + q + t] * invN - mu * mu;
        float s = gamma[q + t] * rsqrtf(var + EPS);
        sc[t] = s; sh[t] = beta[q + t] - mu * s;
    }
    size_t off = ((size_t)(o >> 2) * N + n) * 32 + (o & 3) * 8;
    uint4 hv = *(const uint4*)(h + off);
    uint hu[4] = {hv.x, hv.y, hv.z, hv.w};
    ushort oh[8];
    #pragma unroll
    for (int t = 0; t < 4; ++t) {
        float v0 = h2f((ushort)(hu[t] & 0xffffu));
        float v1 = h2f((ushort)(hu[t] >> 16));
        oh[2*t]   = f2h(fmaxf(v0 * sc[2*t]   + sh[2*t],   0.f));
        oh[2*t+1] = f2h(fmaxf(v1 * sc[2*t+1] + sh[2*t+1], 0.f));
    }
    *(uint4*)(xh + off) = pack8(oh);
}

// ---------------------------------------------------------------------------
// pool over contiguous per-graph row ranges (batch sorted), planar input
// ---------------------------------------------------------------------------
__global__ __launch_bounds__(256) void init_start_k(int* __restrict__ start, int G, int N)
{
    int g = blockIdx.x * 256 + threadIdx.x;
    if (g <= G) start[g] = N;
}

__global__ __launch_bounds__(256) void bound_k(
    const int* __restrict__ batch, int* __restrict__ start, int N)
{
    int n = blockIdx.x * 256 + threadIdx.x;
    if (n >= N) return;
    int b  = batch[n];
    int bp = (n == 0) ? -1 : batch[n - 1];
    for (int g = bp + 1; g <= b; ++g) start[g] = n;
}

__global__ __launch_bounds__(192) void pool_k(
    const ushort* __restrict__ xh, const int* __restrict__ start,
    float* __restrict__ gout, int G, int N)
{
    int g = blockIdx.x;
    int c = threadIdx.x;
    const ushort* base = xh + (size_t)(c >> 5) * N * 32 + (c & 31);
    int r0 = start[g], r1 = start[g + 1];
    float s = 0.f;
    for (int r = r0; r < r1; ++r) s += h2f(base[(size_t)r * 32]);
    float cnt = (float)(r1 - r0);
    gout[(size_t)g * HDIM + c] = s / fmaxf(cnt, 1.f);
}

// ---------------------------------------------------------------------------
// out[g] = dot(g2[g,:], Wout) + bout ; g2 is fp16 chunk-planar
// ---------------------------------------------------------------------------
__global__ __launch_bounds__(64) void out_dot_k(
    const ushort* __restrict__ g2h, const float* __restrict__ Wout,
    const float* __restrict__ bout, float* __restrict__ out, int G)
{
    int gi = blockIdx.x;
    int t = threadIdx.x;
    float s = 0.f;
    #pragma unroll
    for (int j = 0; j < 3; ++j) {
        int c = t + j * 64;
        s += h2f(g2h[((size_t)(c >> 5) * G + gi) * 32 + (c & 31)]) * Wout[c];
    }
    #pragma unroll
    for (int off = 32; off > 0; off >>= 1) s += __shfl_down(s, off, 64);
    if (t == 0) out[gi] = s + bout[0];
}

// ---------------------------------------------------------------------------
extern "C" void kernel_launch(void* const* d_in, const int* in_sizes, int n_in,
                              void* d_out, int out_size, void* d_ws, size_t ws_size,
                              hipStream_t stream)
{
    const float* x      = (const float*)d_in[0];
    const int*   esrc   = (const int*)d_in[1];
    const int*   edst   = (const int*)d_in[2];
    const int*   batch  = (const int*)d_in[3];
    const float* Wrel0  = (const float*)d_in[4];
    const float* brel0  = (const float*)d_in[5];
    const float* Wroot0 = (const float*)d_in[6];
    const float* Wrel   = (const float*)d_in[7];
    const float* brel   = (const float*)d_in[8];
    const float* Wroot  = (const float*)d_in[9];
    const float* gamma  = (const float*)d_in[10];
    const float* beta   = (const float*)d_in[11];
    const float* Wh1    = (const float*)d_in[12];
    const float* bh1    = (const float*)d_in[13];
    const float* Wh2    = (const float*)d_in[14];
    const float* bh2    = (const float*)d_in[15];
    const float* Wout   = (const float*)d_in[16];
    const float* bout   = (const float*)d_in[17];
    float* out = (float*)d_out;

    const int N  = in_sizes[3];           // 100000
    const int E  = in_sizes[1];           // 400000
    const int K0 = in_sizes[0] / N;       // 32
    const int G  = out_size;              // 2000
    const int nBlocks = (N + 255) / 256;
    const float invN = 1.0f / (float)N;

    char* p = (char*)d_ws;
    auto carve = [&](size_t bytes) -> void* {
        void* r = (void*)p; p += (bytes + 255) & ~(size_t)255; return r;
    };
    ushort* bufa_h= (ushort*)carve((size_t)N * HDIM * 2);   // raw conv, planar fp16
    ushort* xh    = (ushort*)carve((size_t)N * HDIM * 2);
    ushort* gh    = (ushort*)carve((size_t)N * HDIM * 2);
    float*  gsum  = (float*) carve((size_t)G * HDIM * 4);
    ushort* gsh   = (ushort*)carve((size_t)G * HDIM * 2);
    ushort* g1h   = (ushort*)carve((size_t)G * HDIM * 2);
    ushort* g2h   = (ushort*)carve((size_t)G * HDIM * 2);
    float*  bnsums= (float*) carve(4 * 2 * HDIM * 4);       // per-layer slices
    float*  degf  = (float*) carve((size_t)N * 4);
    int*    deg   = (int*)   carve((size_t)N * 4);
    int*    row_ptr=(int*)   carve((size_t)(N + 1) * 4);
    int*    cursor= (int*)   carve((size_t)N * 4);
    int*    col   = (int*)   carve((size_t)E * 4);
    int*    bsum  = (int*)   carve((size_t)nBlocks * 4);
    int*    start = (int*)   carve((size_t)(G + 1) * 4);
    ushort* Wrel0f= (ushort*)carve((size_t)K0 * HDIM * 2);
    ushort* Wroot0f=(ushort*)carve((size_t)K0 * HDIM * 2);
    ushort* Wrelf = (ushort*)carve((size_t)3 * HDIM * HDIM * 2);
    ushort* Wrootf= (ushort*)carve((size_t)3 * HDIM * HDIM * 2);
    ushort* Wh1f  = (ushort*)carve((size_t)HDIM * HDIM * 2);
    ushort* Wh2f  = (ushort*)carve((size_t)HDIM * HDIM * 2);

    dim3 b256(256);
    const int eBlocks = (E + 255) / 256;
    const int gemmN = (N + 127) / 128;
    const int gemmG = (G + 127) / 128;

    // ---- weight prep (frag-ordered single fp16 plane)
    {
        int t0 = (K0 >> 5) * 12 * 64;
        int t1 = (HDIM >> 5) * 12 * 64;
        prep_w_k<<<(t0 + 255) / 256, b256, 0, stream>>>(Wrel0,  Wrel0f,  K0, 1);
        prep_w_k<<<(t0 + 255) / 256, b256, 0, stream>>>(Wroot0, Wroot0f, K0, 1);
        prep_w_k<<<(3 * t1 + 255) / 256, b256, 0, stream>>>(Wrel,  Wrelf,  HDIM, 3);
        prep_w_k<<<(3 * t1 + 255) / 256, b256, 0, stream>>>(Wroot, Wrootf, HDIM, 3);
        prep_w_k<<<(t1 + 255) / 256, b256, 0, stream>>>(Wh1, Wh1f, HDIM, 1);
        prep_w_k<<<(t1 + 255) / 256, b256, 0, stream>>>(Wh2, Wh2f, HDIM, 1);
    }
    // x -> planar fp16 (K0=32: planar == row-major)
    conv_planar_k<<<((N * (K0 >> 3)) + 255) / 256, b256, 0, stream>>>(x, xh, N, K0);

    // ---- CSR build
    hipMemsetAsync(deg, 0, N * sizeof(int), stream);
    hipMemsetAsync(bnsums, 0, 4 * 2 * HDIM * sizeof(float), stream);
    hist_k<<<eBlocks, b256, 0, stream>>>(edst, deg, E);
    block_sum_k<<<nBlocks, b256, 0, stream>>>(deg, bsum, N);
    scan_bsum_k<<<1, dim3(512), 0, stream>>>(bsum, nBlocks);
    row_ptr_k<<<nBlocks, b256, 0, stream>>>(deg, bsum, row_ptr, cursor, degf, N, E);
    fill_k<<<eBlocks, b256, 0, stream>>>(esrc, edst, cursor, col, E);

    // ---- graph boundaries for pooling
    init_start_k<<<(G + 256) / 256, b256, 0, stream>>>(start, G, N);
    bound_k<<<nBlocks, b256, 0, stream>>>(batch, start, N);

    // ---- layer 0 (input x, no BN on input)
    gather_h_k<<<((N * (K0 >> 3)) + 255) / 256, b256, 0, stream>>>(
        xh, row_ptr, col, gh, N, K0);
    gemm_mfma_k<true, false, true, true><<<gemmN, b256, 0, stream>>>(
        gh, Wrel0f, xh, Wroot0f, degf, brel0, bufa_h, bnsums, N, K0);

    // ---- layers 1..3: fused BN-apply + gather, then GEMM
    for (int l = 1; l < 4; ++l) {
        const ushort* Wrf = Wrelf  + (size_t)(l - 1) * HDIM * HDIM;
        const ushort* Wtf = Wrootf + (size_t)(l - 1) * HDIM * HDIM;
        const float*  br  = brel   + (size_t)(l - 1) * HDIM;
        gather_bn_k<<<(N * 24 + 255) / 256, b256, 0, stream>>>(
            bufa_h, bnsums + (l - 1) * 2 * HDIM,
            gamma + (l - 1) * HDIM, beta + (l - 1) * HDIM, invN,
            row_ptr, col, xh, gh, N);
        gemm_mfma_k<true, false, true, true><<<gemmN, b256, 0, stream>>>(
            gh, Wrf, xh, Wtf, degf, br, bufa_h, bnsums + l * 2 * HDIM, N, HDIM);
    }
    // final BN (layer 3) -> xh
    bn_apply_h_k<<<(N * 24 + 255) / 256, b256, 0, stream>>>(
        bufa_h, bnsums + 3 * 2 * HDIM, gamma + 3 * HDIM, beta + 3 * HDIM,
        invN, xh, N);

    // ---- pool
    pool_k<<<G, dim3(192), 0, stream>>>(xh, start, gsum, G, N);

    // ---- head MLP (MFMA path, planar fp16 end-to-end)
    conv_planar_k<<<((G * 24) + 255) / 256, b256, 0, stream>>>(gsum, gsh, G, HDIM);
    gemm_mfma_k<false, true, false, false><<<gemmG, b256, 0, stream>>>(
        gsh, Wh1f, nullptr, nullptr, nullptr, bh1, g1h, nullptr, G, HDIM);
    gemm_mfma_k<false, false, false, false><<<gemmG, b256, 0, stream>>>(
        g1h, Wh2f, nullptr, nullptr, nullptr, bh2, g2h, nullptr, G, HDIM);
    out_dot_k<<<G, dim3(64), 0, stream>>>(g2h, Wout, bout, out, G);
}

// Round 13
// 669.837 us; speedup vs baseline: 1.1062x; 1.1062x over previous
//
#include <hip/hip_runtime.h>

#define HDIM 192
#define EPS 1e-5f

typedef __attribute__((ext_vector_type(8))) _Float16 half8;
typedef __attribute__((ext_vector_type(4))) float floatx4;

__device__ __forceinline__ float h2f(ushort u) {
    union { ushort u; _Float16 h; } c; c.u = u; return (float)c.h;
}
__device__ __forceinline__ ushort f2h(float x) {
    _Float16 h = (_Float16)x;           // RTN
    union { _Float16 h; ushort u; } c; c.h = h; return c.u;
}
__device__ __forceinline__ uint4 pack8(const ushort* h) {
    uint4 p;
    p.x = h[0] | ((uint)h[1] << 16); p.y = h[2] | ((uint)h[3] << 16);
    p.z = h[4] | ((uint)h[5] << 16); p.w = h[6] | ((uint)h[7] << 16);
    return p;
}

// Activation planes are CHUNK-PLANAR: element (row, c) lives at
// ((c/32)*Nrow + row)*32 + c%32.  GEMM A-frag loads read a contiguous 1KB
// block per wave; GEMM C-writes, bn/gather all use the same layout.

// ---------------------------------------------------------------------------
// Weight prep: W[K,192] fp32 (nmat stacked) -> frag-ordered SINGLE fp16 plane.
// Per k-chunk (32 k): [ct(12)][lane(64)][j(8)] = 6144 ushorts.
// ---------------------------------------------------------------------------
__global__ __launch_bounds__(256) void prep_w_k(
    const float* __restrict__ W, ushort* __restrict__ Wf, int K, int nmat)
{
    int perMat = (K >> 5) * 12 * 64;
    int idx = blockIdx.x * 256 + threadIdx.x;
    if (idx >= perMat * nmat) return;
    int mat = idx / perMat;
    int r = idx - mat * perMat;
    int lane = r & 63;
    int ct = (r >> 6) % 12;
    int kc = r / (12 * 64);
    int col = ct * 16 + (lane & 15);
    int kb  = kc * 32 + (lane >> 4) * 8;
    const float* Wm = W + (size_t)mat * K * HDIM;
    ushort* base = Wf + (size_t)mat * K * HDIM;
    size_t o = (size_t)kc * 6144 + (size_t)(ct * 64 + lane) * 8;
    #pragma unroll
    for (int j = 0; j < 8; ++j)
        base[o + j] = f2h(Wm[(size_t)(kb + j) * HDIM + col]);
}

// ---------------------------------------------------------------------------
// fp32 row-major [R, C] -> fp16 chunk-planar. One thread per 8 channels.
// ---------------------------------------------------------------------------
__global__ __launch_bounds__(256) void conv_planar_k(
    const float* __restrict__ src, ushort* __restrict__ dst, int R, int C)
{
    int OC = C >> 3;
    int idx = blockIdx.x * 256 + threadIdx.x;
    if (idx >= R * OC) return;
    int r = idx / OC;
    int o = idx - r * OC;
    float4 v0 = ((const float4*)(src + (size_t)r * C + o * 8))[0];
    float4 v1 = ((const float4*)(src + (size_t)r * C + o * 8))[1];
    float v[8] = {v0.x, v0.y, v0.z, v0.w, v1.x, v1.y, v1.z, v1.w};
    ushort h[8];
    #pragma unroll
    for (int t = 0; t < 8; ++t) h[t] = f2h(v[t]);
    *(uint4*)(dst + ((size_t)(o >> 2) * R + r) * 32 + (o & 3) * 8) = pack8(h);
}

// ---------------------------------------------------------------------------
// MFMA GEMM: C[N,192] = A1@W1 (+ A2@W2) + bias-term, optional fused BN stats.
// R11 configuration (best measured: ~68us): block 256 thr / 4 waves, tile
// 64 rows x 192 cols; wave tile 64x48; acc=48 VGPRs, 64 arch VGPR.
// Register double-buffer: chunk c+1's 7 b128 loads issue during chunk c's
// MFMAs.  A chunk-planar fp16; W single fp16 plane frag-major; both straight
// from global, no LDS, no K-loop barriers.  C written fp16 CHUNK-PLANAR.
// ---------------------------------------------------------------------------
template<bool DUAL, bool RELU, bool DEG, bool STATS>
__global__ __launch_bounds__(256, 3) void gemm_mfma_k(
    const ushort* __restrict__ A1h, const ushort* __restrict__ W1f,
    const ushort* __restrict__ A2h, const ushort* __restrict__ W2f,
    const float* __restrict__ degf, const float* __restrict__ bias,
    ushort* __restrict__ C, float* __restrict__ stats, int N, int K)
{
    __shared__ float sstat[2][HDIM];
    const int tid  = threadIdx.x;
    const int wave = tid >> 6;      // 0..3 = column group (48 cols each)
    const int lane = tid & 63;
    const int row0 = blockIdx.x * 64;
    const int m16 = lane & 15;
    const int g4  = lane >> 4;

    if (STATS && tid < HDIM) { sstat[0][tid] = 0.f; sstat[1][tid] = 0.f; }

    int rowid[4];
    #pragma unroll
    for (int s = 0; s < 4; ++s) {
        int rr = row0 + s * 16 + m16; if (rr >= N) rr = N - 1;
        rowid[s] = rr;
    }

    floatx4 acc[4][3];
    #pragma unroll
    for (int s = 0; s < 4; ++s)
        #pragma unroll
        for (int ct = 0; ct < 3; ++ct) acc[s][ct] = (floatx4){0.f, 0.f, 0.f, 0.f};

    const int nkc = K >> 5;
    const int nch = DUAL ? 2 * nkc : nkc;   // always even here

    auto loadc = [&](int c, half8* a, half8* b) {
        bool ph = DUAL && (c >= nkc);
        int kc = ph ? c - nkc : c;
        const ushort* Ap = (ph ? A2h : A1h) + (size_t)kc * N * 32 + g4 * 8;
        #pragma unroll
        for (int s = 0; s < 4; ++s)
            a[s] = *(const half8*)(Ap + (size_t)rowid[s] * 32);
        const ushort* Bp = (ph ? W2f : W1f) + (size_t)kc * 6144
                         + (size_t)(wave * 192 + lane) * 8;
        #pragma unroll
        for (int ct = 0; ct < 3; ++ct)
            b[ct] = *(const half8*)(Bp + ct * 512);
    };
    auto domfma = [&](half8* a, half8* b) {
        #pragma unroll
        for (int ct = 0; ct < 3; ++ct)
            #pragma unroll
            for (int s = 0; s < 4; ++s)
                acc[s][ct] = __builtin_amdgcn_mfma_f32_16x16x32_f16(a[s], b[ct], acc[s][ct], 0, 0, 0);
    };

    half8 a0[4], b0[3], a1[4], b1[3];
    loadc(0, a0, b0);
    for (int cc = 0; cc < nch; cc += 2) {
        if (cc + 1 < nch) loadc(cc + 1, a1, b1);
        domfma(a0, b0);
        if (cc + 2 < nch) loadc(cc + 2, a0, b0);
        if (cc + 1 < nch) domfma(a1, b1);
    }

    if (STATS) __syncthreads();   // sstat zero-init visible

    // epilogue: C/D layout col=lane&15, row=(lane>>4)*4+reg  [m89]
    // C written fp16 chunk-planar: ((col/32)*N + rr)*32 + col%32
    #pragma unroll
    for (int ct = 0; ct < 3; ++ct) {
        int col = wave * 48 + ct * 16 + m16;
        float bv = bias ? bias[col] : 0.f;
        ushort* Cc = C + (size_t)(col >> 5) * N * 32 + (col & 31);
        float lsum = 0.f, lsq = 0.f;
        #pragma unroll
        for (int s = 0; s < 4; ++s) {
            #pragma unroll
            for (int reg = 0; reg < 4; ++reg) {
                int rr = row0 + s * 16 + g4 * 4 + reg;
                if (rr < N) {
                    float v = acc[s][ct][reg] + (DEG ? degf[rr] * bv : bv);
                    if (STATS) { lsum += v; lsq += v * v; }
                    if (RELU) v = fmaxf(v, 0.f);
                    Cc[(size_t)rr * 32] = f2h(v);
                }
            }
        }
        if (STATS) {
            lsum += __shfl_xor(lsum, 16); lsum += __shfl_xor(lsum, 32);
            lsq  += __shfl_xor(lsq, 16);  lsq  += __shfl_xor(lsq, 32);
            if (g4 == 0) {
                atomicAdd(&sstat[0][col], lsum);
                atomicAdd(&sstat[1][col], lsq);
            }
        }
    }
    if (STATS) {
        __syncthreads();
        if (tid < HDIM) {
            atomicAdd(&stats[tid], sstat[0][tid]);
            atomicAdd(&stats[HDIM + tid], sstat[1][tid]);
        }
    }
}

// ---------------------------------------------------------------------------
// CSR construction from edge_dst
// ---------------------------------------------------------------------------
__global__ __launch_bounds__(256) void hist_k(
    const int* __restrict__ dst, int* __restrict__ deg, int E)
{
    int e = blockIdx.x * 256 + threadIdx.x;
    if (e < E) atomicAdd(&deg[dst[e]], 1);
}

__global__ __launch_bounds__(256) void block_sum_k(
    const int* __restrict__ deg, int* __restrict__ bsum, int N)
{
    __shared__ int s[256];
    int t = threadIdx.x;
    int n = blockIdx.x * 256 + t;
    s[t] = (n < N) ? deg[n] : 0;
    __syncthreads();
    for (int off = 128; off > 0; off >>= 1) {
        if (t < off) s[t] += s[t + off];
        __syncthreads();
    }
    if (t == 0) bsum[blockIdx.x] = s[0];
}

__global__ __launch_bounds__(512) void scan_bsum_k(int* __restrict__ bsum, int nb)
{
    __shared__ int s[512];
    int t = threadIdx.x;
    int v = (t < nb) ? bsum[t] : 0;
    s[t] = v;
    __syncthreads();
    for (int off = 1; off < 512; off <<= 1) {
        int u = (t >= off) ? s[t - off] : 0;
        __syncthreads();
        s[t] += u;
        __syncthreads();
    }
    if (t < nb) bsum[t] = s[t] - v;   // exclusive
}

__global__ __launch_bounds__(256) void row_ptr_k(
    const int* __restrict__ deg, const int* __restrict__ bsum,
    int* __restrict__ row_ptr, int* __restrict__ cursor,
    float* __restrict__ degf, int N, int E)
{
    __shared__ int s[256];
    int t = threadIdx.x;
    int n = blockIdx.x * 256 + t;
    int v = (n < N) ? deg[n] : 0;
    s[t] = v;
    __syncthreads();
    for (int off = 1; off < 256; off <<= 1) {
        int u = (t >= off) ? s[t - off] : 0;
        __syncthreads();
        s[t] += u;
        __syncthreads();
    }
    int ex = s[t] - v + bsum[blockIdx.x];
    if (n < N) {
        row_ptr[n] = ex;
        cursor[n]  = ex;
        degf[n]    = (float)v;
    }
    if (blockIdx.x == 0 && t == 0) row_ptr[N] = E;
}

__global__ __launch_bounds__(256) void fill_k(
    const int* __restrict__ src, const int* __restrict__ dst,
    int* __restrict__ cursor, int* __restrict__ col, int E)
{
    int e = blockIdx.x * 256 + threadIdx.x;
    if (e < E) {
        int p = atomicAdd(&cursor[dst[e]], 1);
        col[p] = src[e];
    }
}

// ---------------------------------------------------------------------------
// plain gather (layer 0, no BN): g[n] = sum_j x[col[j]]; planar fp16.
// ---------------------------------------------------------------------------
__global__ __launch_bounds__(256) void gather_h_k(
    const ushort* __restrict__ xh, const int* __restrict__ row_ptr,
    const int* __restrict__ col, ushort* __restrict__ gh, int N, int K)
{
    int OC = K >> 3;
    int idx = blockIdx.x * 256 + threadIdx.x;
    if (idx >= N * OC) return;
    int n = idx / OC;
    int o = idx - n * OC;
    size_t plane = (size_t)(o >> 2) * N * 32 + (o & 3) * 8;
    int j0 = row_ptr[n], j1 = row_ptr[n + 1];
    float acc[8] = {0.f,0.f,0.f,0.f,0.f,0.f,0.f,0.f};
    for (int j = j0; j < j1; ++j) {
        int s = col[j];
        uint4 hv = *(const uint4*)(xh + plane + (size_t)s * 32);
        uint hu[4] = {hv.x, hv.y, hv.z, hv.w};
        #pragma unroll
        for (int t = 0; t < 4; ++t) {
            acc[2*t]   += h2f((ushort)(hu[t] & 0xffffu));
            acc[2*t+1] += h2f((ushort)(hu[t] >> 16));
        }
    }
    ushort oh[8];
    #pragma unroll
    for (int t = 0; t < 8; ++t) oh[t] = f2h(acc[t]);
    *(uint4*)(gh + plane + (size_t)n * 32) = pack8(oh);
}

// ---------------------------------------------------------------------------
// fused BN-apply + gather (layers 1..3, K=192): reads raw conv h (planar),
// computes per-thread BN coeffs from raw sums (no bn_finalize), writes
// xh[n] = relu(bn(h[n])) and gh[n] = sum_j relu(bn(h[col j])).
// ---------------------------------------------------------------------------
__global__ __launch_bounds__(256) void gather_bn_k(
    const ushort* __restrict__ h, const float* __restrict__ stats,
    const float* __restrict__ gamma, const float* __restrict__ beta,
    float invN, const int* __restrict__ row_ptr, const int* __restrict__ col,
    ushort* __restrict__ xh, ushort* __restrict__ gh, int N)
{
    int idx = blockIdx.x * 256 + threadIdx.x;
    if (idx >= N * 24) return;
    int n = idx / 24;
    int o = idx - n * 24;
    int q = o * 8;
    float sc[8], sh[8];
    #pragma unroll
    for (int t = 0; t < 8; ++t) {
        float mu  = stats[q + t] * invN;
        float var = stats[HDIM + q + t] * invN - mu * mu;
        float s = gamma[q + t] * rsqrtf(var + EPS);
        sc[t] = s; sh[t] = beta[q + t] - mu * s;
    }
    size_t plane = (size_t)(o >> 2) * N * 32 + (o & 3) * 8;
    // own row -> xh
    {
        uint4 hv = *(const uint4*)(h + plane + (size_t)n * 32);
        uint hu[4] = {hv.x, hv.y, hv.z, hv.w};
        ushort oh[8];
        #pragma unroll
        for (int t = 0; t < 4; ++t) {
            float v0 = h2f((ushort)(hu[t] & 0xffffu));
            float v1 = h2f((ushort)(hu[t] >> 16));
            oh[2*t]   = f2h(fmaxf(v0 * sc[2*t]   + sh[2*t],   0.f));
            oh[2*t+1] = f2h(fmaxf(v1 * sc[2*t+1] + sh[2*t+1], 0.f));
        }
        *(uint4*)(xh + plane + (size_t)n * 32) = pack8(oh);
    }
    // neighbors -> gh
    int j0 = row_ptr[n], j1 = row_ptr[n + 1];
    float acc[8] = {0.f,0.f,0.f,0.f,0.f,0.f,0.f,0.f};
    for (int j = j0; j < j1; ++j) {
        int s = col[j];
        uint4 hv = *(const uint4*)(h + plane + (size_t)s * 32);
        uint hu[4] = {hv.x, hv.y, hv.z, hv.w};
        #pragma unroll
        for (int t = 0; t < 4; ++t) {
            float v0 = h2f((ushort)(hu[t] & 0xffffu));
            float v1 = h2f((ushort)(hu[t] >> 16));
            acc[2*t]   += fmaxf(v0 * sc[2*t]   + sh[2*t],   0.f);
            acc[2*t+1] += fmaxf(v1 * sc[2*t+1] + sh[2*t+1], 0.f);
        }
    }
    ushort oh[8];
    #pragma unroll
    for (int t = 0; t < 8; ++t) oh[t] = f2h(acc[t]);
    *(uint4*)(gh + plane + (size_t)n * 32) = pack8(oh);
}

// ---------------------------------------------------------------------------
// BN-apply only (after last layer): xh = relu(bn(h)), per-thread coeffs.
// ---------------------------------------------------------------------------
__global__ __launch_bounds__(256) void bn_apply_h_k(
    const ushort* __restrict__ h, const float* __restrict__ stats,
    const float* __restrict__ gamma, const float* __restrict__ beta,
    float invN, ushort* __restrict__ xh, int N)
{
    int idx = blockIdx.x * 256 + threadIdx.x;
    if (idx >= N * 24) return;
    int n = idx / 24;
    int o = idx - n * 24;
    int q = o * 8;
    float sc[8], sh[8];
    #pragma unroll
    for (int t = 0; t < 8; ++t) {
        float mu  = stats[q + t] * invN;
        float var = stats[HDIM + q + t] * invN - mu * mu;
        float s = gamma[q + t] * rsqrtf(var + EPS);
        sc[t] = s; sh[t] = beta[q + t] - mu * s;
    }
    size_t off = ((size_t)(o >> 2) * N + n) * 32 + (o & 3) * 8;
    uint4 hv = *(const uint4*)(h + off);
    uint hu[4] = {hv.x, hv.y, hv.z, hv.w};
    ushort oh[8];
    #pragma unroll
    for (int t = 0; t < 4; ++t) {
        float v0 = h2f((ushort)(hu[t] & 0xffffu));
        float v1 = h2f((ushort)(hu[t] >> 16));
        oh[2*t]   = f2h(fmaxf(v0 * sc[2*t]   + sh[2*t],   0.f));
        oh[2*t+1] = f2h(fmaxf(v1 * sc[2*t+1] + sh[2*t+1], 0.f));
    }
    *(uint4*)(xh + off) = pack8(oh);
}

// ---------------------------------------------------------------------------
// pool over contiguous per-graph row ranges (batch sorted), planar input
// ---------------------------------------------------------------------------
__global__ __launch_bounds__(256) void init_start_k(int* __restrict__ start, int G, int N)
{
    int g = blockIdx.x * 256 + threadIdx.x;
    if (g <= G) start[g] = N;
}

__global__ __launch_bounds__(256) void bound_k(
    const int* __restrict__ batch, int* __restrict__ start, int N)
{
    int n = blockIdx.x * 256 + threadIdx.x;
    if (n >= N) return;
    int b  = batch[n];
    int bp = (n == 0) ? -1 : batch[n - 1];
    for (int g = bp + 1; g <= b; ++g) start[g] = n;
}

__global__ __launch_bounds__(192) void pool_k(
    const ushort* __restrict__ xh, const int* __restrict__ start,
    float* __restrict__ gout, int G, int N)
{
    int g = blockIdx.x;
    int c = threadIdx.x;
    const ushort* base = xh + (size_t)(c >> 5) * N * 32 + (c & 31);
    int r0 = start[g], r1 = start[g + 1];
    float s = 0.f;
    for (int r = r0; r < r1; ++r) s += h2f(base[(size_t)r * 32]);
    float cnt = (float)(r1 - r0);
    gout[(size_t)g * HDIM + c] = s / fmaxf(cnt, 1.f);
}

// ---------------------------------------------------------------------------
// out[g] = dot(g2[g,:], Wout) + bout ; g2 is fp16 chunk-planar
// ---------------------------------------------------------------------------
__global__ __launch_bounds__(64) void out_dot_k(
    const ushort* __restrict__ g2h, const float* __restrict__ Wout,
    const float* __restrict__ bout, float* __restrict__ out, int G)
{
    int gi = blockIdx.x;
    int t = threadIdx.x;
    float s = 0.f;
    #pragma unroll
    for (int j = 0; j < 3; ++j) {
        int c = t + j * 64;
        s += h2f(g2h[((size_t)(c >> 5) * G + gi) * 32 + (c & 31)]) * Wout[c];
    }
    #pragma unroll
    for (int off = 32; off > 0; off >>= 1) s += __shfl_down(s, off, 64);
    if (t == 0) out[gi] = s + bout[0];
}

// ---------------------------------------------------------------------------
extern "C" void kernel_launch(void* const* d_in, const int* in_sizes, int n_in,
                              void* d_out, int out_size, void* d_ws, size_t ws_size,
                              hipStream_t stream)
{
    const float* x      = (const float*)d_in[0];
    const int*   esrc   = (const int*)d_in[1];
    const int*   edst   = (const int*)d_in[2];
    const int*   batch  = (const int*)d_in[3];
    const float* Wrel0  = (const float*)d_in[4];
    const float* brel0  = (const float*)d_in[5];
    const float* Wroot0 = (const float*)d_in[6];
    const float* Wrel   = (const float*)d_in[7];
    const float* brel   = (const float*)d_in[8];
    const float* Wroot  = (const float*)d_in[9];
    const float* gamma  = (const float*)d_in[10];
    const float* beta   = (const float*)d_in[11];
    const float* Wh1    = (const float*)d_in[12];
    const float* bh1    = (const float*)d_in[13];
    const float* Wh2    = (const float*)d_in[14];
    const float* bh2    = (const float*)d_in[15];
    const float* Wout   = (const float*)d_in[16];
    const float* bout   = (const float*)d_in[17];
    float* out = (float*)d_out;

    const int N  = in_sizes[3];           // 100000
    const int E  = in_sizes[1];           // 400000
    const int K0 = in_sizes[0] / N;       // 32
    const int G  = out_size;              // 2000
    const int nBlocks = (N + 255) / 256;
    const float invN = 1.0f / (float)N;

    char* p = (char*)d_ws;
    auto carve = [&](size_t bytes) -> void* {
        void* r = (void*)p; p += (bytes + 255) & ~(size_t)255; return r;
    };
    ushort* bufa_h= (ushort*)carve((size_t)N * HDIM * 2);   // raw conv, planar fp16
    ushort* xh    = (ushort*)carve((size_t)N * HDIM * 2);
    ushort* gh    = (ushort*)carve((size_t)N * HDIM * 2);
    float*  gsum  = (float*) carve((size_t)G * HDIM * 4);
    ushort* gsh   = (ushort*)carve((size_t)G * HDIM * 2);
    ushort* g1h   = (ushort*)carve((size_t)G * HDIM * 2);
    ushort* g2h   = (ushort*)carve((size_t)G * HDIM * 2);
    float*  bnsums= (float*) carve(4 * 2 * HDIM * 4);       // per-layer slices
    float*  degf  = (float*) carve((size_t)N * 4);
    int*    deg   = (int*)   carve((size_t)N * 4);
    int*    row_ptr=(int*)   carve((size_t)(N + 1) * 4);
    int*    cursor= (int*)   carve((size_t)N * 4);
    int*    col   = (int*)   carve((size_t)E * 4);
    int*    bsum  = (int*)   carve((size_t)nBlocks * 4);
    int*    start = (int*)   carve((size_t)(G + 1) * 4);
    ushort* Wrel0f= (ushort*)carve((size_t)K0 * HDIM * 2);
    ushort* Wroot0f=(ushort*)carve((size_t)K0 * HDIM * 2);
    ushort* Wrelf = (ushort*)carve((size_t)3 * HDIM * HDIM * 2);
    ushort* Wrootf= (ushort*)carve((size_t)3 * HDIM * HDIM * 2);
    ushort* Wh1f  = (ushort*)carve((size_t)HDIM * HDIM * 2);
    ushort* Wh2f  = (ushort*)carve((size_t)HDIM * HDIM * 2);

    dim3 b256(256);
    const int eBlocks = (E + 255) / 256;
    const int gemmN = (N + 63) / 64;
    const int gemmG = (G + 63) / 64;

    // ---- weight prep (frag-ordered single fp16 plane)
    {
        int t0 = (K0 >> 5) * 12 * 64;
        int t1 = (HDIM >> 5) * 12 * 64;
        prep_w_k<<<(t0 + 255) / 256, b256, 0, stream>>>(Wrel0,  Wrel0f,  K0, 1);
        prep_w_k<<<(t0 + 255) / 256, b256, 0, stream>>>(Wroot0, Wroot0f, K0, 1);
        prep_w_k<<<(3 * t1 + 255) / 256, b256, 0, stream>>>(Wrel,  Wrelf,  HDIM, 3);
        prep_w_k<<<(3 * t1 + 255) / 256, b256, 0, stream>>>(Wroot, Wrootf, HDIM, 3);
        prep_w_k<<<(t1 + 255) / 256, b256, 0, stream>>>(Wh1, Wh1f, HDIM, 1);
        prep_w_k<<<(t1 + 255) / 256, b256, 0, stream>>>(Wh2, Wh2f, HDIM, 1);
    }
    // x -> planar fp16 (K0=32: planar == row-major)
    conv_planar_k<<<((N * (K0 >> 3)) + 255) / 256, b256, 0, stream>>>(x, xh, N, K0);

    // ---- CSR build
    hipMemsetAsync(deg, 0, N * sizeof(int), stream);
    hipMemsetAsync(bnsums, 0, 4 * 2 * HDIM * sizeof(float), stream);
    hist_k<<<eBlocks, b256, 0, stream>>>(edst, deg, E);
    block_sum_k<<<nBlocks, b256, 0, stream>>>(deg, bsum, N);
    scan_bsum_k<<<1, dim3(512), 0, stream>>>(bsum, nBlocks);
    row_ptr_k<<<nBlocks, b256, 0, stream>>>(deg, bsum, row_ptr, cursor, degf, N, E);
    fill_k<<<eBlocks, b256, 0, stream>>>(esrc, edst, cursor, col, E);

    // ---- graph boundaries for pooling
    init_start_k<<<(G + 256) / 256, b256, 0, stream>>>(start, G, N);
    bound_k<<<nBlocks, b256, 0, stream>>>(batch, start, N);

    // ---- layer 0 (input x, no BN on input)
    gather_h_k<<<((N * (K0 >> 3)) + 255) / 256, b256, 0, stream>>>(
        xh, row_ptr, col, gh, N, K0);
    gemm_mfma_k<true, false, true, true><<<gemmN, b256, 0, stream>>>(
        gh, Wrel0f, xh, Wroot0f, degf, brel0, bufa_h, bnsums, N, K0);

    // ---- layers 1..3: fused BN-apply + gather, then GEMM
    for (int l = 1; l < 4; ++l) {
        const ushort* Wrf = Wrelf  + (size_t)(l - 1) * HDIM * HDIM;
        const ushort* Wtf = Wrootf + (size_t)(l - 1) * HDIM * HDIM;
        const float*  br  = brel   + (size_t)(l - 1) * HDIM;
        gather_bn_k<<<(N * 24 + 255) / 256, b256, 0, stream>>>(
            bufa_h, bnsums + (l - 1) * 2 * HDIM,
            gamma + (l - 1) * HDIM, beta + (l - 1) * HDIM, invN,
            row_ptr, col, xh, gh, N);
        gemm_mfma_k<true, false, true, true><<<gemmN, b256, 0, stream>>>(
            gh, Wrf, xh, Wtf, degf, br, bufa_h, bnsums + l * 2 * HDIM, N, HDIM);
    }
    // final BN (layer 3) -> xh
    bn_apply_h_k<<<(N * 24 + 255) / 256, b256, 0, stream>>>(
        bufa_h, bnsums + 3 * 2 * HDIM, gamma + 3 * HDIM, beta + 3 * HDIM,
        invN, xh, N);

    // ---- pool
    pool_k<<<G, dim3(192), 0, stream>>>(xh, start, gsum, G, N);

    // ---- head MLP (MFMA path, planar fp16 end-to-end)
    conv_planar_k<<<((G * 24) + 255) / 256, b256, 0, stream>>>(gsum, gsh, G, HDIM);
    gemm_mfma_k<false, true, false, false><<<gemmG, b256, 0, stream>>>(
        gsh, Wh1f, nullptr, nullptr, nullptr, bh1, g1h, nullptr, G, HDIM);
    gemm_mfma_k<false, false, false, false><<<gemmG, b256, 0, stream>>>(
        g1h, Wh2f, nullptr, nullptr, nullptr, bh2, g2h, nullptr, G, HDIM);
    out_dot_k<<<G, dim3(64), 0, stream>>>(g2h, Wout, bout, out, G);
}

// Round 14
// 638.203 us; speedup vs baseline: 1.1610x; 1.0496x over previous
//
#include <hip/hip_runtime.h>

#define HDIM 192
#define EPS 1e-5f

typedef __attribute__((ext_vector_type(8))) _Float16 half8;
typedef __attribute__((ext_vector_type(4))) float floatx4;

__device__ __forceinline__ float h2f(ushort u) {
    union { ushort u; _Float16 h; } c; c.u = u; return (float)c.h;
}
__device__ __forceinline__ ushort f2h(float x) {
    _Float16 h = (_Float16)x;           // RTN
    union { _Float16 h; ushort u; } c; c.h = h; return c.u;
}
__device__ __forceinline__ uint4 pack8(const ushort* h) {
    uint4 p;
    p.x = h[0] | ((uint)h[1] << 16); p.y = h[2] | ((uint)h[3] << 16);
    p.z = h[4] | ((uint)h[5] << 16); p.w = h[6] | ((uint)h[7] << 16);
    return p;
}

// Activation planes are CHUNK-PLANAR: element (row, c) lives at
// ((c/32)*Nrow + row)*32 + c%32.

// ---------------------------------------------------------------------------
// Merged weight prep: all 10 matrices in ONE launch.
// Each: W[K,192] fp32 -> frag-ordered single fp16 plane
// (per k-chunk: [ct(12)][lane(64)][j(8)] = 6144 ushorts).
// ---------------------------------------------------------------------------
struct PrepArgs {
    const float* src[6];
    ushort*      dst[6];
    int K[6];
    int off[7];       // thread offsets (per entry: nmat*(K/32)*12*64)
};

__global__ __launch_bounds__(256) void prep_all_k(PrepArgs a)
{
    int idx = blockIdx.x * 256 + threadIdx.x;
    if (idx >= a.off[6]) return;
    int i = 0;
    #pragma unroll
    for (int t = 1; t < 6; ++t) if (idx >= a.off[t]) i = t;
    int r = idx - a.off[i];
    int K = a.K[i];
    int perMat = (K >> 5) * 12 * 64;
    int mat = r / perMat;
    r -= mat * perMat;
    int lane = r & 63;
    int ct = (r >> 6) % 12;
    int kc = r / (12 * 64);
    int col = ct * 16 + (lane & 15);
    int kb  = kc * 32 + (lane >> 4) * 8;
    const float* Wm = a.src[i] + (size_t)mat * K * HDIM;
    ushort* base = a.dst[i] + (size_t)mat * K * HDIM;
    size_t o = (size_t)kc * 6144 + (size_t)(ct * 64 + lane) * 8;
    #pragma unroll
    for (int j = 0; j < 8; ++j)
        base[o + j] = f2h(Wm[(size_t)(kb + j) * HDIM + col]);
}

// ---------------------------------------------------------------------------
// fp32 row-major [R, C] -> fp16 chunk-planar. One thread per 8 channels.
// ---------------------------------------------------------------------------
__global__ __launch_bounds__(256) void conv_planar_k(
    const float* __restrict__ src, ushort* __restrict__ dst, int R, int C)
{
    int OC = C >> 3;
    int idx = blockIdx.x * 256 + threadIdx.x;
    if (idx >= R * OC) return;
    int r = idx / OC;
    int o = idx - r * OC;
    float4 v0 = ((const float4*)(src + (size_t)r * C + o * 8))[0];
    float4 v1 = ((const float4*)(src + (size_t)r * C + o * 8))[1];
    float v[8] = {v0.x, v0.y, v0.z, v0.w, v1.x, v1.y, v1.z, v1.w};
    ushort h[8];
    #pragma unroll
    for (int t = 0; t < 8; ++t) h[t] = f2h(v[t]);
    *(uint4*)(dst + ((size_t)(o >> 2) * R + r) * 32 + (o & 3) * 8) = pack8(h);
}

// ---------------------------------------------------------------------------
// MFMA GEMM (R11/R13 structure, now 4 waves/SIMD): block 256 thr / 4 waves,
// tile 64 rows x 192 cols; wave tile 64x48; acc=48 AGPR + 64 VGPR = 112
// unified regs <= 128 cap for (256,4).  Register double-buffer: chunk c+1's
// 7 b128 loads issue during chunk c's 12 MFMAs.  A chunk-planar fp16;
// W single fp16 plane frag-major; straight from global, no LDS staging,
// no K-loop barriers.  C written fp16 CHUNK-PLANAR; BN stats from fp32 accs.
// ---------------------------------------------------------------------------
template<bool DUAL, bool RELU, bool DEG, bool STATS>
__global__ __launch_bounds__(256, 4) void gemm_mfma_k(
    const ushort* __restrict__ A1h, const ushort* __restrict__ W1f,
    const ushort* __restrict__ A2h, const ushort* __restrict__ W2f,
    const float* __restrict__ degf, const float* __restrict__ bias,
    ushort* __restrict__ C, float* __restrict__ stats, int N, int K)
{
    __shared__ float sstat[2][HDIM];
    const int tid  = threadIdx.x;
    const int wave = tid >> 6;      // 0..3 = column group (48 cols each)
    const int lane = tid & 63;
    const int row0 = blockIdx.x * 64;
    const int m16 = lane & 15;
    const int g4  = lane >> 4;

    if (STATS && tid < HDIM) { sstat[0][tid] = 0.f; sstat[1][tid] = 0.f; }

    int rowid[4];
    #pragma unroll
    for (int s = 0; s < 4; ++s) {
        int rr = row0 + s * 16 + m16; if (rr >= N) rr = N - 1;
        rowid[s] = rr;
    }

    floatx4 acc[4][3];
    #pragma unroll
    for (int s = 0; s < 4; ++s)
        #pragma unroll
        for (int ct = 0; ct < 3; ++ct) acc[s][ct] = (floatx4){0.f, 0.f, 0.f, 0.f};

    const int nkc = K >> 5;
    const int nch = DUAL ? 2 * nkc : nkc;   // always even here

    auto loadc = [&](int c, half8* a, half8* b) {
        bool ph = DUAL && (c >= nkc);
        int kc = ph ? c - nkc : c;
        const ushort* Ap = (ph ? A2h : A1h) + (size_t)kc * N * 32 + g4 * 8;
        #pragma unroll
        for (int s = 0; s < 4; ++s)
            a[s] = *(const half8*)(Ap + (size_t)rowid[s] * 32);
        const ushort* Bp = (ph ? W2f : W1f) + (size_t)kc * 6144
                         + (size_t)(wave * 192 + lane) * 8;
        #pragma unroll
        for (int ct = 0; ct < 3; ++ct)
            b[ct] = *(const half8*)(Bp + ct * 512);
    };
    auto domfma = [&](half8* a, half8* b) {
        #pragma unroll
        for (int ct = 0; ct < 3; ++ct)
            #pragma unroll
            for (int s = 0; s < 4; ++s)
                acc[s][ct] = __builtin_amdgcn_mfma_f32_16x16x32_f16(a[s], b[ct], acc[s][ct], 0, 0, 0);
    };

    half8 a0[4], b0[3], a1[4], b1[3];
    loadc(0, a0, b0);
    for (int cc = 0; cc < nch; cc += 2) {
        if (cc + 1 < nch) loadc(cc + 1, a1, b1);
        domfma(a0, b0);
        if (cc + 2 < nch) loadc(cc + 2, a0, b0);
        if (cc + 1 < nch) domfma(a1, b1);
    }

    if (STATS) __syncthreads();   // sstat zero-init visible

    // epilogue: C/D layout col=lane&15, row=(lane>>4)*4+reg  [m89]
    #pragma unroll
    for (int ct = 0; ct < 3; ++ct) {
        int col = wave * 48 + ct * 16 + m16;
        float bv = bias ? bias[col] : 0.f;
        ushort* Cc = C + (size_t)(col >> 5) * N * 32 + (col & 31);
        float lsum = 0.f, lsq = 0.f;
        #pragma unroll
        for (int s = 0; s < 4; ++s) {
            #pragma unroll
            for (int reg = 0; reg < 4; ++reg) {
                int rr = row0 + s * 16 + g4 * 4 + reg;
                if (rr < N) {
                    float v = acc[s][ct][reg] + (DEG ? degf[rr] * bv : bv);
                    if (STATS) { lsum += v; lsq += v * v; }
                    if (RELU) v = fmaxf(v, 0.f);
                    Cc[(size_t)rr * 32] = f2h(v);
                }
            }
        }
        if (STATS) {
            lsum += __shfl_xor(lsum, 16); lsum += __shfl_xor(lsum, 32);
            lsq  += __shfl_xor(lsq, 16);  lsq  += __shfl_xor(lsq, 32);
            if (g4 == 0) {
                atomicAdd(&sstat[0][col], lsum);
                atomicAdd(&sstat[1][col], lsq);
            }
        }
    }
    if (STATS) {
        __syncthreads();
        if (tid < HDIM) {
            atomicAdd(&stats[tid], sstat[0][tid]);
            atomicAdd(&stats[HDIM + tid], sstat[1][tid]);
        }
    }
}

// ---------------------------------------------------------------------------
// CSR construction from edge_dst
// ---------------------------------------------------------------------------
__global__ __launch_bounds__(256) void hist_k(
    const int* __restrict__ dst, int* __restrict__ deg, int E)
{
    int e = blockIdx.x * 256 + threadIdx.x;
    if (e < E) atomicAdd(&deg[dst[e]], 1);
}

__global__ __launch_bounds__(256) void block_sum_k(
    const int* __restrict__ deg, int* __restrict__ bsum, int N)
{
    __shared__ int s[256];
    int t = threadIdx.x;
    int n = blockIdx.x * 256 + t;
    s[t] = (n < N) ? deg[n] : 0;
    __syncthreads();
    for (int off = 128; off > 0; off >>= 1) {
        if (t < off) s[t] += s[t + off];
        __syncthreads();
    }
    if (t == 0) bsum[blockIdx.x] = s[0];
}

__global__ __launch_bounds__(512) void scan_bsum_k(int* __restrict__ bsum, int nb)
{
    __shared__ int s[512];
    int t = threadIdx.x;
    int v = (t < nb) ? bsum[t] : 0;
    s[t] = v;
    __syncthreads();
    for (int off = 1; off < 512; off <<= 1) {
        int u = (t >= off) ? s[t - off] : 0;
        __syncthreads();
        s[t] += u;
        __syncthreads();
    }
    if (t < nb) bsum[t] = s[t] - v;   // exclusive
}

__global__ __launch_bounds__(256) void row_ptr_k(
    const int* __restrict__ deg, const int* __restrict__ bsum,
    int* __restrict__ row_ptr, int* __restrict__ cursor,
    float* __restrict__ degf, int N, int E)
{
    __shared__ int s[256];
    int t = threadIdx.x;
    int n = blockIdx.x * 256 + t;
    int v = (n < N) ? deg[n] : 0;
    s[t] = v;
    __syncthreads();
    for (int off = 1; off < 256; off <<= 1) {
        int u = (t >= off) ? s[t - off] : 0;
        __syncthreads();
        s[t] += u;
        __syncthreads();
    }
    int ex = s[t] - v + bsum[blockIdx.x];
    if (n < N) {
        row_ptr[n] = ex;
        cursor[n]  = ex;
        degf[n]    = (float)v;
    }
    if (blockIdx.x == 0 && t == 0) row_ptr[N] = E;
}

__global__ __launch_bounds__(256) void fill_k(
    const int* __restrict__ src, const int* __restrict__ dst,
    int* __restrict__ cursor, int* __restrict__ col, int E)
{
    int e = blockIdx.x * 256 + threadIdx.x;
    if (e < E) {
        int p = atomicAdd(&cursor[dst[e]], 1);
        col[p] = src[e];
    }
}

// ---------------------------------------------------------------------------
// plain gather (layer 0, no BN): g[n] = sum_j x[col[j]]; planar fp16.
// ---------------------------------------------------------------------------
__global__ __launch_bounds__(256) void gather_h_k(
    const ushort* __restrict__ xh, const int* __restrict__ row_ptr,
    const int* __restrict__ col, ushort* __restrict__ gh, int N, int K)
{
    int OC = K >> 3;
    int idx = blockIdx.x * 256 + threadIdx.x;
    if (idx >= N * OC) return;
    int n = idx / OC;
    int o = idx - n * OC;
    size_t plane = (size_t)(o >> 2) * N * 32 + (o & 3) * 8;
    int j0 = row_ptr[n], j1 = row_ptr[n + 1];
    float acc[8] = {0.f,0.f,0.f,0.f,0.f,0.f,0.f,0.f};
    for (int j = j0; j < j1; ++j) {
        int s = col[j];
        uint4 hv = *(const uint4*)(xh + plane + (size_t)s * 32);
        uint hu[4] = {hv.x, hv.y, hv.z, hv.w};
        #pragma unroll
        for (int t = 0; t < 4; ++t) {
            acc[2*t]   += h2f((ushort)(hu[t] & 0xffffu));
            acc[2*t+1] += h2f((ushort)(hu[t] >> 16));
        }
    }
    ushort oh[8];
    #pragma unroll
    for (int t = 0; t < 8; ++t) oh[t] = f2h(acc[t]);
    *(uint4*)(gh + plane + (size_t)n * 32) = pack8(oh);
}

// ---------------------------------------------------------------------------
// fused BN-apply + gather (layers 1..3): reads raw conv h (planar), computes
// per-thread BN coeffs from raw sums, writes xh[n] = relu(bn(h[n])) and
// gh[n] = sum_j relu(bn(h[col j])).
// ---------------------------------------------------------------------------
__global__ __launch_bounds__(256) void gather_bn_k(
    const ushort* __restrict__ h, const float* __restrict__ stats,
    const float* __restrict__ gamma, const float* __restrict__ beta,
    float invN, const int* __restrict__ row_ptr, const int* __restrict__ col,
    ushort* __restrict__ xh, ushort* __restrict__ gh, int N)
{
    int idx = blockIdx.x * 256 + threadIdx.x;
    if (idx >= N * 24) return;
    int n = idx / 24;
    int o = idx - n * 24;
    int q = o * 8;
    float sc[8], sh[8];
    #pragma unroll
    for (int t = 0; t < 8; ++t) {
        float mu  = stats[q + t] * invN;
        float var = stats[HDIM + q + t] * invN - mu * mu;
        float s = gamma[q + t] * rsqrtf(var + EPS);
        sc[t] = s; sh[t] = beta[q + t] - mu * s;
    }
    size_t plane = (size_t)(o >> 2) * N * 32 + (o & 3) * 8;
    // own row -> xh
    {
        uint4 hv = *(const uint4*)(h + plane + (size_t)n * 32);
        uint hu[4] = {hv.x, hv.y, hv.z, hv.w};
        ushort oh[8];
        #pragma unroll
        for (int t = 0; t < 4; ++t) {
            float v0 = h2f((ushort)(hu[t] & 0xffffu));
            float v1 = h2f((ushort)(hu[t] >> 16));
            oh[2*t]   = f2h(fmaxf(v0 * sc[2*t]   + sh[2*t],   0.f));
            oh[2*t+1] = f2h(fmaxf(v1 * sc[2*t+1] + sh[2*t+1], 0.f));
        }
        *(uint4*)(xh + plane + (size_t)n * 32) = pack8(oh);
    }
    // neighbors -> gh
    int j0 = row_ptr[n], j1 = row_ptr[n + 1];
    float acc[8] = {0.f,0.f,0.f,0.f,0.f,0.f,0.f,0.f};
    for (int j = j0; j < j1; ++j) {
        int s = col[j];
        uint4 hv = *(const uint4*)(h + plane + (size_t)s * 32);
        uint hu[4] = {hv.x, hv.y, hv.z, hv.w};
        #pragma unroll
        for (int t = 0; t < 4; ++t) {
            float v0 = h2f((ushort)(hu[t] & 0xffffu));
            float v1 = h2f((ushort)(hu[t] >> 16));
            acc[2*t]   += fmaxf(v0 * sc[2*t]   + sh[2*t],   0.f);
            acc[2*t+1] += fmaxf(v1 * sc[2*t+1] + sh[2*t+1], 0.f);
        }
    }
    ushort oh[8];
    #pragma unroll
    for (int t = 0; t < 8; ++t) oh[t] = f2h(acc[t]);
    *(uint4*)(gh + plane + (size_t)n * 32) = pack8(oh);
}

// ---------------------------------------------------------------------------
// fused final-BN + mean-pool: block per graph, thread per channel.
// Graph row range via binary search in sorted batch[]. Output fp16 planar
// (Nrow=G), feeding the head GEMM directly.
// ---------------------------------------------------------------------------
__global__ __launch_bounds__(192) void pool_bn_k(
    const ushort* __restrict__ h, const float* __restrict__ stats,
    const float* __restrict__ gamma, const float* __restrict__ beta,
    float invN, const int* __restrict__ batch,
    ushort* __restrict__ gsh, int G, int N)
{
    __shared__ int bounds[2];
    int g = blockIdx.x;
    int c = threadIdx.x;
    if (c < 2) {
        int key = g + c;
        int lo = 0, hi = N;
        while (lo < hi) {
            int mid = (lo + hi) >> 1;
            if (batch[mid] < key) lo = mid + 1; else hi = mid;
        }
        bounds[c] = lo;
    }
    __syncthreads();
    int r0 = bounds[0], r1 = bounds[1];
    float mu  = stats[c] * invN;
    float var = stats[HDIM + c] * invN - mu * mu;
    float sc  = gamma[c] * rsqrtf(var + EPS);
    float sh  = beta[c] - mu * sc;
    const ushort* base = h + (size_t)(c >> 5) * N * 32 + (c & 31);
    float s = 0.f;
    for (int r = r0; r < r1; ++r)
        s += fmaxf(h2f(base[(size_t)r * 32]) * sc + sh, 0.f);
    float m = s / fmaxf((float)(r1 - r0), 1.f);
    gsh[((size_t)(c >> 5) * G + g) * 32 + (c & 31)] = f2h(m);
}

// ---------------------------------------------------------------------------
// out[g] = dot(g2[g,:], Wout) + bout ; g2 is fp16 chunk-planar
// ---------------------------------------------------------------------------
__global__ __launch_bounds__(64) void out_dot_k(
    const ushort* __restrict__ g2h, const float* __restrict__ Wout,
    const float* __restrict__ bout, float* __restrict__ out, int G)
{
    int gi = blockIdx.x;
    int t = threadIdx.x;
    float s = 0.f;
    #pragma unroll
    for (int j = 0; j < 3; ++j) {
        int c = t + j * 64;
        s += h2f(g2h[((size_t)(c >> 5) * G + gi) * 32 + (c & 31)]) * Wout[c];
    }
    #pragma unroll
    for (int off = 32; off > 0; off >>= 1) s += __shfl_down(s, off, 64);
    if (t == 0) out[gi] = s + bout[0];
}

// ---------------------------------------------------------------------------
extern "C" void kernel_launch(void* const* d_in, const int* in_sizes, int n_in,
                              void* d_out, int out_size, void* d_ws, size_t ws_size,
                              hipStream_t stream)
{
    const float* x      = (const float*)d_in[0];
    const int*   esrc   = (const int*)d_in[1];
    const int*   edst   = (const int*)d_in[2];
    const int*   batch  = (const int*)d_in[3];
    const float* Wrel0  = (const float*)d_in[4];
    const float* brel0  = (const float*)d_in[5];
    const float* Wroot0 = (const float*)d_in[6];
    const float* Wrel   = (const float*)d_in[7];
    const float* brel   = (const float*)d_in[8];
    const float* Wroot  = (const float*)d_in[9];
    const float* gamma  = (const float*)d_in[10];
    const float* beta   = (const float*)d_in[11];
    const float* Wh1    = (const float*)d_in[12];
    const float* bh1    = (const float*)d_in[13];
    const float* Wh2    = (const float*)d_in[14];
    const float* bh2    = (const float*)d_in[15];
    const float* Wout   = (const float*)d_in[16];
    const float* bout   = (const float*)d_in[17];
    float* out = (float*)d_out;

    const int N  = in_sizes[3];           // 100000
    const int E  = in_sizes[1];           // 400000
    const int K0 = in_sizes[0] / N;       // 32
    const int G  = out_size;              // 2000
    const int nBlocks = (N + 255) / 256;
    const float invN = 1.0f / (float)N;

    char* p = (char*)d_ws;
    auto carve = [&](size_t bytes) -> void* {
        void* r = (void*)p; p += (bytes + 255) & ~(size_t)255; return r;
    };
    ushort* bufa_h= (ushort*)carve((size_t)N * HDIM * 2);   // raw conv, planar fp16
    ushort* xh    = (ushort*)carve((size_t)N * HDIM * 2);
    ushort* gh    = (ushort*)carve((size_t)N * HDIM * 2);
    ushort* gsh   = (ushort*)carve((size_t)G * HDIM * 2);
    ushort* g1h   = (ushort*)carve((size_t)G * HDIM * 2);
    ushort* g2h   = (ushort*)carve((size_t)G * HDIM * 2);
    // deg + bnsums adjacent -> single memset
    int*    deg   = (int*)   carve((size_t)N * 4);
    float*  bnsums= (float*) carve(4 * 2 * HDIM * 4);
    size_t  zspan = (char*)(bnsums + 4 * 2 * HDIM) - (char*)deg;
    float*  degf  = (float*) carve((size_t)N * 4);
    int*    row_ptr=(int*)   carve((size_t)(N + 1) * 4);
    int*    cursor= (int*)   carve((size_t)N * 4);
    int*    col   = (int*)   carve((size_t)E * 4);
    int*    bsum  = (int*)   carve((size_t)nBlocks * 4);
    ushort* Wrel0f= (ushort*)carve((size_t)K0 * HDIM * 2);
    ushort* Wroot0f=(ushort*)carve((size_t)K0 * HDIM * 2);
    ushort* Wrelf = (ushort*)carve((size_t)3 * HDIM * HDIM * 2);
    ushort* Wrootf= (ushort*)carve((size_t)3 * HDIM * HDIM * 2);
    ushort* Wh1f  = (ushort*)carve((size_t)HDIM * HDIM * 2);
    ushort* Wh2f  = (ushort*)carve((size_t)HDIM * HDIM * 2);

    dim3 b256(256);
    const int eBlocks = (E + 255) / 256;
    const int gemmN = (N + 63) / 64;
    const int gemmG = (G + 63) / 64;

    // ---- merged weight prep (1 launch)
    {
        PrepArgs a;
        int t0 = (K0 >> 5) * 12 * 64;        // 768
        int t1 = (HDIM >> 5) * 12 * 64;      // 4608
        a.src[0] = Wrel0;  a.dst[0] = Wrel0f;  a.K[0] = K0;
        a.src[1] = Wroot0; a.dst[1] = Wroot0f; a.K[1] = K0;
        a.src[2] = Wrel;   a.dst[2] = Wrelf;   a.K[2] = HDIM;
        a.src[3] = Wroot;  a.dst[3] = Wrootf;  a.K[3] = HDIM;
        a.src[4] = Wh1;    a.dst[4] = Wh1f;    a.K[4] = HDIM;
        a.src[5] = Wh2;    a.dst[5] = Wh2f;    a.K[5] = HDIM;
        a.off[0] = 0;
        a.off[1] = a.off[0] + t0;
        a.off[2] = a.off[1] + t0;
        a.off[3] = a.off[2] + 3 * t1;
        a.off[4] = a.off[3] + 3 * t1;
        a.off[5] = a.off[4] + t1;
        a.off[6] = a.off[5] + t1;
        prep_all_k<<<(a.off[6] + 255) / 256, b256, 0, stream>>>(a);
    }
    // x -> planar fp16 (K0=32: planar == row-major)
    conv_planar_k<<<((N * (K0 >> 3)) + 255) / 256, b256, 0, stream>>>(x, xh, N, K0);

    // ---- CSR build
    hipMemsetAsync(deg, 0, zspan, stream);   // zeros deg + bnsums
    hist_k<<<eBlocks, b256, 0, stream>>>(edst, deg, E);
    block_sum_k<<<nBlocks, b256, 0, stream>>>(deg, bsum, N);
    scan_bsum_k<<<1, dim3(512), 0, stream>>>(bsum, nBlocks);
    row_ptr_k<<<nBlocks, b256, 0, stream>>>(deg, bsum, row_ptr, cursor, degf, N, E);
    fill_k<<<eBlocks, b256, 0, stream>>>(esrc, edst, cursor, col, E);

    // ---- layer 0 (input x, no BN on input)
    gather_h_k<<<((N * (K0 >> 3)) + 255) / 256, b256, 0, stream>>>(
        xh, row_ptr, col, gh, N, K0);
    gemm_mfma_k<true, false, true, true><<<gemmN, b256, 0, stream>>>(
        gh, Wrel0f, xh, Wroot0f, degf, brel0, bufa_h, bnsums, N, K0);

    // ---- layers 1..3: fused BN-apply + gather, then GEMM
    for (int l = 1; l < 4; ++l) {
        const ushort* Wrf = Wrelf  + (size_t)(l - 1) * HDIM * HDIM;
        const ushort* Wtf = Wrootf + (size_t)(l - 1) * HDIM * HDIM;
        const float*  br  = brel   + (size_t)(l - 1) * HDIM;
        gather_bn_k<<<(N * 24 + 255) / 256, b256, 0, stream>>>(
            bufa_h, bnsums + (l - 1) * 2 * HDIM,
            gamma + (l - 1) * HDIM, beta + (l - 1) * HDIM, invN,
            row_ptr, col, xh, gh, N);
        gemm_mfma_k<true, false, true, true><<<gemmN, b256, 0, stream>>>(
            gh, Wrf, xh, Wtf, degf, br, bufa_h, bnsums + l * 2 * HDIM, N, HDIM);
    }

    // ---- fused final BN + mean pool -> fp16 planar head input
    pool_bn_k<<<G, dim3(192), 0, stream>>>(
        bufa_h, bnsums + 3 * 2 * HDIM, gamma + 3 * HDIM, beta + 3 * HDIM,
        invN, batch, gsh, G, N);

    // ---- head MLP (MFMA path, planar fp16 end-to-end)
    gemm_mfma_k<false, true, false, false><<<gemmG, b256, 0, stream>>>(
        gsh, Wh1f, nullptr, nullptr, nullptr, bh1, g1h, nullptr, G, HDIM);
    gemm_mfma_k<false, false, false, false><<<gemmG, b256, 0, stream>>>(
        g1h, Wh2f, nullptr, nullptr, nullptr, bh2, g2h, nullptr, G, HDIM);
    out_dot_k<<<G, dim3(64), 0, stream>>>(g2h, Wout, bout, out, G);
}